// Round 1
// baseline (583.277 us; speedup 1.0000x reference)
//
#include <hip/hip_runtime.h>
#include <stdint.h>

typedef __bf16 bf16;
typedef bf16 bf16x8 __attribute__((ext_vector_type(8)));
typedef bf16 bf16x4 __attribute__((ext_vector_type(4)));
typedef float f32x4 __attribute__((ext_vector_type(4)));

#define MFMA16(a, b, c) __builtin_amdgcn_mfma_f32_16x16x32_bf16(a, b, c, 0, 0, 0)

__device__ __forceinline__ void gll16(const void* g, void* l) {
    __builtin_amdgcn_global_load_lds(
        (const __attribute__((address_space(1))) void*)g,
        (__attribute__((address_space(3))) void*)l, 16, 0, 0);
}

__device__ __forceinline__ float bflo(uint32_t u) {
    union { uint32_t i; float f; } x; x.i = u << 16; return x.f;
}
__device__ __forceinline__ float bfhi(uint32_t u) {
    union { uint32_t i; float f; } x; x.i = u & 0xffff0000u; return x.f;
}
__device__ __forceinline__ uint32_t packcv(float c, float v) {
    union { bf16 b[2]; uint32_t u; } p;
    p.b[0] = (bf16)c; p.b[1] = (bf16)v; return p.u;
}

// ---------------- W fp32 -> bf16 conversion (tiny) ----------------
__global__ __launch_bounds__(256) void convw_kernel(
    const float* __restrict__ Whg, const float* __restrict__ Wout,
    bf16* __restrict__ Whg_bf, bf16* __restrict__ Wout_bf) {
    int i = blockIdx.x * 256 + threadIdx.x;  // 196608 float4 granules total
    if (i < 131072) {
        f32x4 v = ((const f32x4*)Whg)[i];
        ((bf16x4*)Whg_bf)[i] = __builtin_convertvector(v, bf16x4);
    } else {
        int j = i - 131072;  // < 65536
        f32x4 v = ((const f32x4*)Wout)[j];
        ((bf16x4*)Wout_bf)[j] = __builtin_convertvector(v, bf16x4);
    }
}

// ---------------- GEMM1: hg = x @ W_hg^T, fused sigmoid epilogue -> packed (c,v) ----------------
// A = x (M,512) fp32 row-major; W = W_hg bf16 (1024,512) row-major.
// Block computes 128 rows x 128 cols of BOTH hidden (W rows n0..) and gate (W rows 512+n0..).
__global__ __launch_bounds__(256) void gemm1_kernel(
    const float* __restrict__ X, const bf16* __restrict__ W,
    uint32_t* __restrict__ CV) {
    constexpr int K = 512;
    __shared__ bf16 As[128 * 32];
    __shared__ bf16 Bh[128 * 32];
    __shared__ bf16 Bg[128 * 32];

    const int t = threadIdx.x;
    const size_t m0 = (size_t)blockIdx.x * 128;
    const int n0 = blockIdx.y * 128;
    const int w = t >> 6, lane = t & 63;
    const int wm = (w >> 1) * 64, wn = (w & 1) * 64;
    const int r16 = lane & 15, quad = lane >> 4;

    f32x4 ah[4][4] = {};
    f32x4 ag[4][4] = {};

    const float* xg = X + m0 * K;

    for (int k0 = 0; k0 < K; k0 += 32) {
        __syncthreads();
        // stage A tile (fp32 -> bf16): 128x32, 1024 float4 granules, 4/thread
        #pragma unroll
        for (int r = 0; r < 4; ++r) {
            int g = r * 256 + t;
            int row = g >> 3, c4 = g & 7;
            f32x4 v = *(const f32x4*)(xg + (size_t)row * K + k0 + c4 * 4);
            *(bf16x4*)&As[row * 32 + c4 * 4] = __builtin_convertvector(v, bf16x4);
        }
        // stage B tiles (bf16, async direct-to-LDS): 512 granules of 16B each, 2/thread
        #pragma unroll
        for (int r = 0; r < 2; ++r) {
            int g = r * 256 + t;
            int row = g >> 2, c8 = g & 3;
            gll16(W + (size_t)(n0 + row) * K + k0 + c8 * 8, &Bh[g * 8]);
            gll16(W + (size_t)(512 + n0 + row) * K + k0 + c8 * 8, &Bg[g * 8]);
        }
        __syncthreads();
        bf16x8 af[4], bhf[4], bgf[4];
        #pragma unroll
        for (int i = 0; i < 4; ++i)
            af[i] = *(const bf16x8*)&As[(wm + i * 16 + r16) * 32 + quad * 8];
        #pragma unroll
        for (int i = 0; i < 4; ++i) {
            bhf[i] = *(const bf16x8*)&Bh[(wn + i * 16 + r16) * 32 + quad * 8];
            bgf[i] = *(const bf16x8*)&Bg[(wn + i * 16 + r16) * 32 + quad * 8];
        }
        #pragma unroll
        for (int mi = 0; mi < 4; ++mi)
            #pragma unroll
            for (int ni = 0; ni < 4; ++ni) {
                ah[mi][ni] = MFMA16(af[mi], bhf[ni], ah[mi][ni]);
                ag[mi][ni] = MFMA16(af[mi], bgf[ni], ag[mi][ni]);
            }
    }
    // epilogue: c = sigmoid(-gate), v = sigmoid(gate)*g(hidden); pack to bf16 pair
    #pragma unroll
    for (int mi = 0; mi < 4; ++mi)
        #pragma unroll
        for (int ni = 0; ni < 4; ++ni)
            #pragma unroll
            for (int r = 0; r < 4; ++r) {
                size_t row = m0 + wm + mi * 16 + quad * 4 + r;
                int col = n0 + wn + ni * 16 + r16;
                float hid = ah[mi][ni][r], gat = ag[mi][ni][r];
                float z = 1.f / (1.f + __expf(-gat));   // sigmoid(gate)
                float c = 1.f / (1.f + __expf(gat));    // sigmoid(-gate)
                float gv = hid >= 0.f ? hid + 0.5f : 1.f / (1.f + __expf(-hid));
                CV[row * 512 + col] = packcv(c, z * gv);
            }
}

// ---------------- scan: h[t] = c[t]*h[t-1] + v[t], chunked 3-phase ----------------
#define NC 64
#define CHUNK 128  // 8192 / NC

__global__ __launch_bounds__(256) void scan1_kernel(
    const uint32_t* __restrict__ CV, float2* __restrict__ agg) {
    int idx = blockIdx.x * 256 + threadIdx.x;  // 8*64*512 = 262144
    int h = idx & 511;
    int ch = (idx >> 9) & (NC - 1);
    int b = idx >> 15;
    const uint32_t* p = CV + (((size_t)b * 8192 + (size_t)ch * CHUNK) * 512 + h);
    float C = 1.f, V = 0.f;
    for (int tt = 0; tt < CHUNK; tt += 8) {
        uint32_t u[8];
        #pragma unroll
        for (int j = 0; j < 8; ++j) u[j] = p[(size_t)(tt + j) * 512];
        #pragma unroll
        for (int j = 0; j < 8; ++j) {
            float c = bflo(u[j]), v = bfhi(u[j]);
            C *= c;
            V = c * V + v;
        }
    }
    agg[idx] = make_float2(C, V);
}

__global__ __launch_bounds__(256) void scan2_kernel(
    const float2* __restrict__ agg, float* __restrict__ h0) {
    int idx = blockIdx.x * 256 + threadIdx.x;  // 4096
    int h = idx & 511;
    int b = idx >> 9;
    float hr = 0.f;
    for (int ch = 0; ch < NC; ++ch) {
        size_t o = ((size_t)b * NC + ch) * 512 + h;
        h0[o] = hr;
        float2 a = agg[o];
        hr = a.x * hr + a.y;
    }
}

__global__ __launch_bounds__(256) void scan3_kernel(
    const uint32_t* __restrict__ CV, const float* __restrict__ h0,
    bf16* __restrict__ Hbf, float* __restrict__ hn) {
    int idx = blockIdx.x * 256 + threadIdx.x;
    int h = idx & 511;
    int ch = (idx >> 9) & (NC - 1);
    int b = idx >> 15;
    size_t base = ((size_t)b * 8192 + (size_t)ch * CHUNK) * 512 + h;
    const uint32_t* p = CV + base;
    bf16* q = Hbf + base;
    float hcur = h0[idx];
    for (int tt = 0; tt < CHUNK; tt += 8) {
        uint32_t u[8];
        #pragma unroll
        for (int j = 0; j < 8; ++j) u[j] = p[(size_t)(tt + j) * 512];
        #pragma unroll
        for (int j = 0; j < 8; ++j) {
            float c = bflo(u[j]), v = bfhi(u[j]);
            hcur = c * hcur + v;
            q[(size_t)(tt + j) * 512] = (bf16)hcur;
        }
    }
    if (ch == NC - 1) hn[b * 512 + h] = hcur;  // fp32 h_n output
}

// ---------------- GEMM2: out = h @ W_out^T (bf16 MFMA, fp32 out) ----------------
__global__ __launch_bounds__(256) void gemm2_kernel(
    const bf16* __restrict__ Ah, const bf16* __restrict__ Wo,
    float* __restrict__ Out) {
    constexpr int K = 512;
    __shared__ bf16 As[128 * 32];
    __shared__ bf16 Bs[128 * 32];
    const int t = threadIdx.x;
    const size_t m0 = (size_t)blockIdx.x * 128;
    const int n0 = blockIdx.y * 128;
    const int w = t >> 6, lane = t & 63;
    const int wm = (w >> 1) * 64, wn = (w & 1) * 64;
    const int r16 = lane & 15, quad = lane >> 4;
    f32x4 acc[4][4] = {};
    for (int k0 = 0; k0 < K; k0 += 32) {
        __syncthreads();
        #pragma unroll
        for (int r = 0; r < 2; ++r) {
            int g = r * 256 + t;
            int row = g >> 2, c8 = g & 3;
            gll16(Ah + (m0 + row) * K + k0 + c8 * 8, &As[g * 8]);
            gll16(Wo + (size_t)(n0 + row) * K + k0 + c8 * 8, &Bs[g * 8]);
        }
        __syncthreads();
        bf16x8 af[4], bf[4];
        #pragma unroll
        for (int i = 0; i < 4; ++i)
            af[i] = *(const bf16x8*)&As[(wm + i * 16 + r16) * 32 + quad * 8];
        #pragma unroll
        for (int i = 0; i < 4; ++i)
            bf[i] = *(const bf16x8*)&Bs[(wn + i * 16 + r16) * 32 + quad * 8];
        #pragma unroll
        for (int mi = 0; mi < 4; ++mi)
            #pragma unroll
            for (int ni = 0; ni < 4; ++ni)
                acc[mi][ni] = MFMA16(af[mi], bf[ni], acc[mi][ni]);
    }
    #pragma unroll
    for (int mi = 0; mi < 4; ++mi)
        #pragma unroll
        for (int ni = 0; ni < 4; ++ni)
            #pragma unroll
            for (int r = 0; r < 4; ++r) {
                size_t row = m0 + wm + mi * 16 + quad * 4 + r;
                int col = n0 + wn + ni * 16 + r16;
                Out[row * 512 + col] = acc[mi][ni][r];
            }
}

extern "C" void kernel_launch(void* const* d_in, const int* in_sizes, int n_in,
                              void* d_out, int out_size, void* d_ws, size_t ws_size,
                              hipStream_t stream) {
    const float* x    = (const float*)d_in[0];
    // d_in[1] = is_init (unused by reference)
    const float* Whg  = (const float*)d_in[2];
    const float* Wout = (const float*)d_in[3];
    float* out = (float*)d_out;

    const int M = 8 * 8192;  // 65536

    char* ws = (char*)d_ws;
    bf16*     Whg_bf  = (bf16*)ws;                               // 1 MB
    bf16*     Wout_bf = (bf16*)(ws + 1048576);                   // 0.5 MB
    uint32_t* CV      = (uint32_t*)(ws + 1572864);               // 134 MB
    bf16*     Hbf     = (bf16*)(ws + 135790592);                 // 67 MB
    float2*   agg     = (float2*)(ws + 202899456);               // 2 MB
    float*    h0      = (float*)(ws + 204996608);                // 1 MB
    // total 206045184 bytes

    convw_kernel<<<768, 256, 0, stream>>>(Whg, Wout, Whg_bf, Wout_bf);

    dim3 g1(M / 128, 4);
    gemm1_kernel<<<g1, 256, 0, stream>>>(x, Whg_bf, CV);

    scan1_kernel<<<(8 * NC * 512) / 256, 256, 0, stream>>>(CV, agg);
    scan2_kernel<<<16, 256, 0, stream>>>(agg, h0);
    scan3_kernel<<<(8 * NC * 512) / 256, 256, 0, stream>>>(CV, h0, Hbf,
                                                           out + (size_t)M * 512);

    dim3 g2(M / 128, 4);
    gemm2_kernel<<<g2, 256, 0, stream>>>(Hbf, Wout_bf, out);
}

// Round 2
// 555.315 us; speedup vs baseline: 1.0504x; 1.0504x over previous
//
#include <hip/hip_runtime.h>
#include <stdint.h>

typedef __bf16 bf16;
typedef bf16 bf16x8 __attribute__((ext_vector_type(8)));
typedef bf16 bf16x4 __attribute__((ext_vector_type(4)));
typedef float f32x4 __attribute__((ext_vector_type(4)));

#define MFMA16(a, b, c) __builtin_amdgcn_mfma_f32_16x16x32_bf16(a, b, c, 0, 0, 0)

__device__ __forceinline__ void gll16(const void* g, void* l) {
    __builtin_amdgcn_global_load_lds(
        (const __attribute__((address_space(1))) void*)g,
        (__attribute__((address_space(3))) void*)l, 16, 0, 0);
}

__device__ __forceinline__ float bflo(uint32_t u) {
    union { uint32_t i; float f; } x; x.i = u << 16; return x.f;
}
__device__ __forceinline__ float bfhi(uint32_t u) {
    union { uint32_t i; float f; } x; x.i = u & 0xffff0000u; return x.f;
}
__device__ __forceinline__ uint32_t packcv(float c, float v) {
    union { bf16 b[2]; uint32_t u; } p;
    p.b[0] = (bf16)c; p.b[1] = (bf16)v; return p.u;
}

// ---------------- fp32 -> bf16 conversion: X (8.39M granules) + Whg + Wout ----------------
// granule = float4 -> bf16x4
__global__ __launch_bounds__(256) void conv_kernel(
    const float* __restrict__ X, const float* __restrict__ Whg,
    const float* __restrict__ Wout, bf16* __restrict__ Xbf,
    bf16* __restrict__ Whg_bf, bf16* __restrict__ Wout_bf) {
    int i = blockIdx.x * 256 + threadIdx.x;
    if (i < 8388608) {
        f32x4 v = ((const f32x4*)X)[i];
        ((bf16x4*)Xbf)[i] = __builtin_convertvector(v, bf16x4);
    } else if (i < 8388608 + 131072) {
        int j = i - 8388608;
        f32x4 v = ((const f32x4*)Whg)[j];
        ((bf16x4*)Whg_bf)[j] = __builtin_convertvector(v, bf16x4);
    } else {
        int j = i - (8388608 + 131072);  // < 65536
        f32x4 v = ((const f32x4*)Wout)[j];
        ((bf16x4*)Wout_bf)[j] = __builtin_convertvector(v, bf16x4);
    }
}

// ---------------- GEMM1: hg = x @ W_hg^T, fused sigmoid epilogue -> packed (c,v) ----------------
// A = Xbf (M,512) bf16 row-major; W = W_hg bf16 (1024,512) row-major.
// Block computes 128 rows x 128 cols of BOTH hidden (W rows n0..) and gate (W rows 512+n0..).
// All staging via global_load_lds width=16 (no VGPR round-trip).
__global__ __launch_bounds__(256) void gemm1_kernel(
    const bf16* __restrict__ Xbf, const bf16* __restrict__ W,
    uint32_t* __restrict__ CV) {
    constexpr int K = 512;
    __shared__ bf16 As[128 * 32];
    __shared__ bf16 Bh[128 * 32];
    __shared__ bf16 Bg[128 * 32];

    const int t = threadIdx.x;
    const size_t m0 = (size_t)blockIdx.x * 128;
    const int n0 = blockIdx.y * 128;
    const int w = t >> 6, lane = t & 63;
    const int wm = (w >> 1) * 64, wn = (w & 1) * 64;
    const int r16 = lane & 15, quad = lane >> 4;

    f32x4 ah[4][4] = {};
    f32x4 ag[4][4] = {};

    for (int k0 = 0; k0 < K; k0 += 32) {
        __syncthreads();
        // stage A + Bh + Bg tiles: each 128x32 bf16 = 512 granules of 16B, 2/thread
        #pragma unroll
        for (int r = 0; r < 2; ++r) {
            int g = r * 256 + t;
            int row = g >> 2, c8 = g & 3;
            gll16(Xbf + (m0 + row) * K + k0 + c8 * 8, &As[g * 8]);
            gll16(W + (size_t)(n0 + row) * K + k0 + c8 * 8, &Bh[g * 8]);
            gll16(W + (size_t)(512 + n0 + row) * K + k0 + c8 * 8, &Bg[g * 8]);
        }
        __syncthreads();
        bf16x8 af[4], bhf[4], bgf[4];
        #pragma unroll
        for (int i = 0; i < 4; ++i)
            af[i] = *(const bf16x8*)&As[(wm + i * 16 + r16) * 32 + quad * 8];
        #pragma unroll
        for (int i = 0; i < 4; ++i) {
            bhf[i] = *(const bf16x8*)&Bh[(wn + i * 16 + r16) * 32 + quad * 8];
            bgf[i] = *(const bf16x8*)&Bg[(wn + i * 16 + r16) * 32 + quad * 8];
        }
        #pragma unroll
        for (int mi = 0; mi < 4; ++mi)
            #pragma unroll
            for (int ni = 0; ni < 4; ++ni) {
                ah[mi][ni] = MFMA16(af[mi], bhf[ni], ah[mi][ni]);
                ag[mi][ni] = MFMA16(af[mi], bgf[ni], ag[mi][ni]);
            }
    }
    // epilogue: c = sigmoid(-gate), v = sigmoid(gate)*g(hidden); pack to bf16 pair
    #pragma unroll
    for (int mi = 0; mi < 4; ++mi)
        #pragma unroll
        for (int ni = 0; ni < 4; ++ni)
            #pragma unroll
            for (int r = 0; r < 4; ++r) {
                size_t row = m0 + wm + mi * 16 + quad * 4 + r;
                int col = n0 + wn + ni * 16 + r16;
                float hid = ah[mi][ni][r], gat = ag[mi][ni][r];
                float z = 1.f / (1.f + __expf(-gat));   // sigmoid(gate)
                float c = 1.f / (1.f + __expf(gat));    // sigmoid(-gate)
                float gv = hid >= 0.f ? hid + 0.5f : 1.f / (1.f + __expf(-hid));
                CV[row * 512 + col] = packcv(c, z * gv);
            }
}

// ---------------- scan: h[t] = c[t]*h[t-1] + v[t], chunked 3-phase ----------------
#define NC 64
#define CHUNK 128  // 8192 / NC

__global__ __launch_bounds__(256) void scan1_kernel(
    const uint32_t* __restrict__ CV, float2* __restrict__ agg) {
    int idx = blockIdx.x * 256 + threadIdx.x;  // 8*64*512 = 262144
    int h = idx & 511;
    int ch = (idx >> 9) & (NC - 1);
    int b = idx >> 15;
    const uint32_t* p = CV + (((size_t)b * 8192 + (size_t)ch * CHUNK) * 512 + h);
    float C = 1.f, V = 0.f;
    for (int tt = 0; tt < CHUNK; tt += 8) {
        uint32_t u[8];
        #pragma unroll
        for (int j = 0; j < 8; ++j) u[j] = p[(size_t)(tt + j) * 512];
        #pragma unroll
        for (int j = 0; j < 8; ++j) {
            float c = bflo(u[j]), v = bfhi(u[j]);
            C *= c;
            V = c * V + v;
        }
    }
    agg[idx] = make_float2(C, V);
}

__global__ __launch_bounds__(256) void scan2_kernel(
    const float2* __restrict__ agg, float* __restrict__ h0) {
    int idx = blockIdx.x * 256 + threadIdx.x;  // 4096
    int h = idx & 511;
    int b = idx >> 9;
    float hr = 0.f;
    for (int ch = 0; ch < NC; ++ch) {
        size_t o = ((size_t)b * NC + ch) * 512 + h;
        h0[o] = hr;
        float2 a = agg[o];
        hr = a.x * hr + a.y;
    }
}

__global__ __launch_bounds__(256) void scan3_kernel(
    const uint32_t* __restrict__ CV, const float* __restrict__ h0,
    bf16* __restrict__ Hbf, float* __restrict__ hn) {
    int idx = blockIdx.x * 256 + threadIdx.x;
    int h = idx & 511;
    int ch = (idx >> 9) & (NC - 1);
    int b = idx >> 15;
    size_t base = ((size_t)b * 8192 + (size_t)ch * CHUNK) * 512 + h;
    const uint32_t* p = CV + base;
    bf16* q = Hbf + base;
    float hcur = h0[idx];
    for (int tt = 0; tt < CHUNK; tt += 8) {
        uint32_t u[8];
        #pragma unroll
        for (int j = 0; j < 8; ++j) u[j] = p[(size_t)(tt + j) * 512];
        #pragma unroll
        for (int j = 0; j < 8; ++j) {
            float c = bflo(u[j]), v = bfhi(u[j]);
            hcur = c * hcur + v;
            q[(size_t)(tt + j) * 512] = (bf16)hcur;
        }
    }
    if (ch == NC - 1) hn[b * 512 + h] = hcur;  // fp32 h_n output
}

// ---------------- GEMM2: out = h @ W_out^T (bf16 MFMA, fp32 out) ----------------
__global__ __launch_bounds__(256) void gemm2_kernel(
    const bf16* __restrict__ Ah, const bf16* __restrict__ Wo,
    float* __restrict__ Out) {
    constexpr int K = 512;
    __shared__ bf16 As[128 * 32];
    __shared__ bf16 Bs[128 * 32];
    const int t = threadIdx.x;
    const size_t m0 = (size_t)blockIdx.x * 128;
    const int n0 = blockIdx.y * 128;
    const int w = t >> 6, lane = t & 63;
    const int wm = (w >> 1) * 64, wn = (w & 1) * 64;
    const int r16 = lane & 15, quad = lane >> 4;
    f32x4 acc[4][4] = {};
    for (int k0 = 0; k0 < K; k0 += 32) {
        __syncthreads();
        #pragma unroll
        for (int r = 0; r < 2; ++r) {
            int g = r * 256 + t;
            int row = g >> 2, c8 = g & 3;
            gll16(Ah + (m0 + row) * K + k0 + c8 * 8, &As[g * 8]);
            gll16(Wo + (size_t)(n0 + row) * K + k0 + c8 * 8, &Bs[g * 8]);
        }
        __syncthreads();
        bf16x8 af[4], bf[4];
        #pragma unroll
        for (int i = 0; i < 4; ++i)
            af[i] = *(const bf16x8*)&As[(wm + i * 16 + r16) * 32 + quad * 8];
        #pragma unroll
        for (int i = 0; i < 4; ++i)
            bf[i] = *(const bf16x8*)&Bs[(wn + i * 16 + r16) * 32 + quad * 8];
        #pragma unroll
        for (int mi = 0; mi < 4; ++mi)
            #pragma unroll
            for (int ni = 0; ni < 4; ++ni)
                acc[mi][ni] = MFMA16(af[mi], bf[ni], acc[mi][ni]);
    }
    #pragma unroll
    for (int mi = 0; mi < 4; ++mi)
        #pragma unroll
        for (int ni = 0; ni < 4; ++ni)
            #pragma unroll
            for (int r = 0; r < 4; ++r) {
                size_t row = m0 + wm + mi * 16 + quad * 4 + r;
                int col = n0 + wn + ni * 16 + r16;
                Out[row * 512 + col] = acc[mi][ni][r];
            }
}

extern "C" void kernel_launch(void* const* d_in, const int* in_sizes, int n_in,
                              void* d_out, int out_size, void* d_ws, size_t ws_size,
                              hipStream_t stream) {
    const float* x    = (const float*)d_in[0];
    // d_in[1] = is_init (unused by reference)
    const float* Whg  = (const float*)d_in[2];
    const float* Wout = (const float*)d_in[3];
    float* out = (float*)d_out;

    const int M = 8 * 8192;  // 65536

    // Workspace layout (total 206045184 B, same as round 1):
    //   [0, 67108864)           Xbf  (later aliased by Hbf — Xbf dead after gemm1)
    //   [67108864, 68157440)    Whg_bf
    //   [68157440, 68681728)    Wout_bf
    //   [68681728, 202899456)   CV
    //   [202899456, 204996608)  agg
    //   [204996608, 206045184)  h0
    char* ws = (char*)d_ws;
    bf16*     Xbf     = (bf16*)ws;
    bf16*     Hbf     = (bf16*)ws;                 // alias: valid, see ordering
    bf16*     Whg_bf  = (bf16*)(ws + 67108864);
    bf16*     Wout_bf = (bf16*)(ws + 68157440);
    uint32_t* CV      = (uint32_t*)(ws + 68681728);
    float2*   agg     = (float2*)(ws + 202899456);
    float*    h0      = (float*)(ws + 204996608);

    // 8388608 (X) + 131072 (Whg) + 65536 (Wout) granules = 8585216 -> 33536 blocks
    conv_kernel<<<33536, 256, 0, stream>>>(x, Whg, Wout, Xbf, Whg_bf, Wout_bf);

    dim3 g1(M / 128, 4);
    gemm1_kernel<<<g1, 256, 0, stream>>>(Xbf, Whg_bf, CV);

    scan1_kernel<<<(8 * NC * 512) / 256, 256, 0, stream>>>(CV, agg);
    scan2_kernel<<<16, 256, 0, stream>>>(agg, h0);
    scan3_kernel<<<(8 * NC * 512) / 256, 256, 0, stream>>>(CV, h0, Hbf,
                                                           out + (size_t)M * 512);

    dim3 g2(M / 128, 4);
    gemm2_kernel<<<g2, 256, 0, stream>>>(Hbf, Wout_bf, out);
}

// Round 3
// 489.578 us; speedup vs baseline: 1.1914x; 1.1343x over previous
//
#include <hip/hip_runtime.h>
#include <stdint.h>

typedef __bf16 bf16;
typedef bf16 bf16x8 __attribute__((ext_vector_type(8)));
typedef bf16 bf16x4 __attribute__((ext_vector_type(4)));
typedef float f32x4 __attribute__((ext_vector_type(4)));

#define MFMA16(a, b, c) __builtin_amdgcn_mfma_f32_16x16x32_bf16(a, b, c, 0, 0, 0)

__device__ __forceinline__ void gll16(const void* g, void* l) {
    __builtin_amdgcn_global_load_lds(
        (const __attribute__((address_space(1))) void*)g,
        (__attribute__((address_space(3))) void*)l, 16, 0, 0);
}

__device__ __forceinline__ float frcp(float x) { return __builtin_amdgcn_rcpf(x); }

__device__ __forceinline__ float bflo(uint32_t u) {
    union { uint32_t i; float f; } x; x.i = u << 16; return x.f;
}
__device__ __forceinline__ float bfhi(uint32_t u) {
    union { uint32_t i; float f; } x; x.i = u & 0xffff0000u; return x.f;
}
__device__ __forceinline__ uint32_t packcv(float c, float v) {
    union { bf16 b[2]; uint32_t u; } p;
    p.b[0] = (bf16)c; p.b[1] = (bf16)v; return p.u;
}

// ---------------- fp32 -> bf16 conversion: X + Whg + Wout ----------------
__global__ __launch_bounds__(256) void conv_kernel(
    const float* __restrict__ X, const float* __restrict__ Whg,
    const float* __restrict__ Wout, bf16* __restrict__ Xbf,
    bf16* __restrict__ Whg_bf, bf16* __restrict__ Wout_bf) {
    int i = blockIdx.x * 256 + threadIdx.x;
    if (i < 8388608) {
        f32x4 v = ((const f32x4*)X)[i];
        ((bf16x4*)Xbf)[i] = __builtin_convertvector(v, bf16x4);
    } else if (i < 8388608 + 131072) {
        int j = i - 8388608;
        f32x4 v = ((const f32x4*)Whg)[j];
        ((bf16x4*)Whg_bf)[j] = __builtin_convertvector(v, bf16x4);
    } else {
        int j = i - (8388608 + 131072);  // < 65536
        f32x4 v = ((const f32x4*)Wout)[j];
        ((bf16x4*)Wout_bf)[j] = __builtin_convertvector(v, bf16x4);
    }
}

// ---------------- GEMM1: hg = x @ W_hg^T, fused sigmoid epilogue -> packed (c,v) ----------------
// BK=64, XOR-8 swizzled LDS granules (granule = 16 B = 8 bf16).
// LDS tile: 128 rows x 64 cols; physical granule for (row, c8) is (row*8 + (c8 ^ (row&7))).
__global__ __launch_bounds__(256) void gemm1_kernel(
    const bf16* __restrict__ Xbf, const bf16* __restrict__ W,
    uint32_t* __restrict__ CV) {
    constexpr int K = 512;
    __shared__ bf16 As[128 * 64];
    __shared__ bf16 Bh[128 * 64];
    __shared__ bf16 Bg[128 * 64];

    const int t = threadIdx.x;
    const size_t m0 = (size_t)blockIdx.x * 128;
    const int n0 = blockIdx.y * 128;
    const int w = t >> 6, lane = t & 63;
    const int wm = (w >> 1) * 64, wn = (w & 1) * 64;
    const int r16 = lane & 15, quad = lane >> 4;
    const int sw = r16 & 7;  // row&7 for all fragment rows this lane touches

    f32x4 ah[4][4] = {};
    f32x4 ag[4][4] = {};

    for (int k0 = 0; k0 < K; k0 += 64) {
        __syncthreads();
        // stage A + Bh + Bg tiles: each 1024 granules of 16B, 4/thread/tile
        #pragma unroll
        for (int r = 0; r < 4; ++r) {
            int g = r * 256 + t;
            int row = g >> 3;
            int c8 = (g & 7) ^ (row & 7);  // swizzled source granule
            gll16(Xbf + (m0 + row) * K + k0 + c8 * 8, &As[g * 8]);
            gll16(W + (size_t)(n0 + row) * K + k0 + c8 * 8, &Bh[g * 8]);
            gll16(W + (size_t)(512 + n0 + row) * K + k0 + c8 * 8, &Bg[g * 8]);
        }
        __syncthreads();
        #pragma unroll
        for (int kk = 0; kk < 2; ++kk) {
            const int kg = kk * 4 + quad;
            bf16x8 af[4], bhf[4], bgf[4];
            #pragma unroll
            for (int i = 0; i < 4; ++i) {
                int arow = wm + i * 16 + r16;
                af[i] = *(const bf16x8*)&As[arow * 64 + (kg ^ sw) * 8];
            }
            #pragma unroll
            for (int i = 0; i < 4; ++i) {
                int brow = wn + i * 16 + r16;
                bhf[i] = *(const bf16x8*)&Bh[brow * 64 + (kg ^ sw) * 8];
                bgf[i] = *(const bf16x8*)&Bg[brow * 64 + (kg ^ sw) * 8];
            }
            #pragma unroll
            for (int mi = 0; mi < 4; ++mi)
                #pragma unroll
                for (int ni = 0; ni < 4; ++ni) {
                    ah[mi][ni] = MFMA16(af[mi], bhf[ni], ah[mi][ni]);
                    ag[mi][ni] = MFMA16(af[mi], bgf[ni], ag[mi][ni]);
                }
        }
    }
    // epilogue: z = sigmoid(gate); c = 1-z; v = z*g(hidden)
    #pragma unroll
    for (int mi = 0; mi < 4; ++mi)
        #pragma unroll
        for (int ni = 0; ni < 4; ++ni)
            #pragma unroll
            for (int r = 0; r < 4; ++r) {
                size_t row = m0 + wm + mi * 16 + quad * 4 + r;
                int col = n0 + wn + ni * 16 + r16;
                float hid = ah[mi][ni][r], gat = ag[mi][ni][r];
                float z = frcp(1.f + __expf(-gat));     // sigmoid(gate)
                float c = 1.f - z;                      // sigmoid(-gate)
                float gv = hid >= 0.f ? hid + 0.5f : frcp(1.f + __expf(-hid));
                CV[row * 512 + col] = packcv(c, z * gv);
            }
}

// ---------------- scan: h[t] = c[t]*h[t-1] + v[t], chunked 3-phase ----------------
#define NC 64
#define CHUNK 128  // 8192 / NC

__global__ __launch_bounds__(256) void scan1_kernel(
    const uint32_t* __restrict__ CV, float2* __restrict__ agg) {
    int idx = blockIdx.x * 256 + threadIdx.x;  // 8*64*512 = 262144
    int h = idx & 511;
    int ch = (idx >> 9) & (NC - 1);
    int b = idx >> 15;
    const uint32_t* p = CV + (((size_t)b * 8192 + (size_t)ch * CHUNK) * 512 + h);
    float C = 1.f, V = 0.f;
    for (int tt = 0; tt < CHUNK; tt += 8) {
        uint32_t u[8];
        #pragma unroll
        for (int j = 0; j < 8; ++j) u[j] = p[(size_t)(tt + j) * 512];
        #pragma unroll
        for (int j = 0; j < 8; ++j) {
            float c = bflo(u[j]), v = bfhi(u[j]);
            C *= c;
            V = c * V + v;
        }
    }
    agg[idx] = make_float2(C, V);
}

__global__ __launch_bounds__(256) void scan2_kernel(
    const float2* __restrict__ agg, float* __restrict__ h0) {
    int idx = blockIdx.x * 256 + threadIdx.x;  // 4096
    int h = idx & 511;
    int b = idx >> 9;
    float hr = 0.f;
    for (int ch = 0; ch < NC; ++ch) {
        size_t o = ((size_t)b * NC + ch) * 512 + h;
        h0[o] = hr;
        float2 a = agg[o];
        hr = a.x * hr + a.y;
    }
}

__global__ __launch_bounds__(256) void scan3_kernel(
    const uint32_t* __restrict__ CV, const float* __restrict__ h0,
    bf16* __restrict__ Hbf, float* __restrict__ hn) {
    int idx = blockIdx.x * 256 + threadIdx.x;
    int h = idx & 511;
    int ch = (idx >> 9) & (NC - 1);
    int b = idx >> 15;
    size_t base = ((size_t)b * 8192 + (size_t)ch * CHUNK) * 512 + h;
    const uint32_t* p = CV + base;
    bf16* q = Hbf + base;
    float hcur = h0[idx];
    for (int tt = 0; tt < CHUNK; tt += 8) {
        uint32_t u[8];
        #pragma unroll
        for (int j = 0; j < 8; ++j) u[j] = p[(size_t)(tt + j) * 512];
        #pragma unroll
        for (int j = 0; j < 8; ++j) {
            float c = bflo(u[j]), v = bfhi(u[j]);
            hcur = c * hcur + v;
            q[(size_t)(tt + j) * 512] = (bf16)hcur;
        }
    }
    if (ch == NC - 1) hn[b * 512 + h] = hcur;  // fp32 h_n output
}

// ---------------- GEMM2: out = h @ W_out^T (bf16 MFMA, fp32 out) ----------------
// BK=64, XOR-8 swizzle, same as gemm1.
__global__ __launch_bounds__(256) void gemm2_kernel(
    const bf16* __restrict__ Ah, const bf16* __restrict__ Wo,
    float* __restrict__ Out) {
    constexpr int K = 512;
    __shared__ bf16 As[128 * 64];
    __shared__ bf16 Bs[128 * 64];
    const int t = threadIdx.x;
    const size_t m0 = (size_t)blockIdx.x * 128;
    const int n0 = blockIdx.y * 128;
    const int w = t >> 6, lane = t & 63;
    const int wm = (w >> 1) * 64, wn = (w & 1) * 64;
    const int r16 = lane & 15, quad = lane >> 4;
    const int sw = r16 & 7;
    f32x4 acc[4][4] = {};
    for (int k0 = 0; k0 < K; k0 += 64) {
        __syncthreads();
        #pragma unroll
        for (int r = 0; r < 4; ++r) {
            int g = r * 256 + t;
            int row = g >> 3;
            int c8 = (g & 7) ^ (row & 7);
            gll16(Ah + (m0 + row) * K + k0 + c8 * 8, &As[g * 8]);
            gll16(Wo + (size_t)(n0 + row) * K + k0 + c8 * 8, &Bs[g * 8]);
        }
        __syncthreads();
        #pragma unroll
        for (int kk = 0; kk < 2; ++kk) {
            const int kg = kk * 4 + quad;
            bf16x8 af[4], bf[4];
            #pragma unroll
            for (int i = 0; i < 4; ++i)
                af[i] = *(const bf16x8*)&As[(wm + i * 16 + r16) * 64 + (kg ^ sw) * 8];
            #pragma unroll
            for (int i = 0; i < 4; ++i)
                bf[i] = *(const bf16x8*)&Bs[(wn + i * 16 + r16) * 64 + (kg ^ sw) * 8];
            #pragma unroll
            for (int mi = 0; mi < 4; ++mi)
                #pragma unroll
                for (int ni = 0; ni < 4; ++ni)
                    acc[mi][ni] = MFMA16(af[mi], bf[ni], acc[mi][ni]);
        }
    }
    #pragma unroll
    for (int mi = 0; mi < 4; ++mi)
        #pragma unroll
        for (int ni = 0; ni < 4; ++ni)
            #pragma unroll
            for (int r = 0; r < 4; ++r) {
                size_t row = m0 + wm + mi * 16 + quad * 4 + r;
                int col = n0 + wn + ni * 16 + r16;
                Out[row * 512 + col] = acc[mi][ni][r];
            }
}

extern "C" void kernel_launch(void* const* d_in, const int* in_sizes, int n_in,
                              void* d_out, int out_size, void* d_ws, size_t ws_size,
                              hipStream_t stream) {
    const float* x    = (const float*)d_in[0];
    // d_in[1] = is_init (unused by reference)
    const float* Whg  = (const float*)d_in[2];
    const float* Wout = (const float*)d_in[3];
    float* out = (float*)d_out;

    const int M = 8 * 8192;  // 65536

    // Workspace layout (total 206045184 B):
    //   [0, 67108864)           Xbf  (later aliased by Hbf — Xbf dead after gemm1)
    //   [67108864, 68157440)    Whg_bf
    //   [68157440, 68681728)    Wout_bf
    //   [68681728, 202899456)   CV
    //   [202899456, 204996608)  agg
    //   [204996608, 206045184)  h0
    char* ws = (char*)d_ws;
    bf16*     Xbf     = (bf16*)ws;
    bf16*     Hbf     = (bf16*)ws;                 // alias: valid, see ordering
    bf16*     Whg_bf  = (bf16*)(ws + 67108864);
    bf16*     Wout_bf = (bf16*)(ws + 68157440);
    uint32_t* CV      = (uint32_t*)(ws + 68681728);
    float2*   agg     = (float2*)(ws + 202899456);
    float*    h0      = (float*)(ws + 204996608);

    conv_kernel<<<33536, 256, 0, stream>>>(x, Whg, Wout, Xbf, Whg_bf, Wout_bf);

    dim3 g1(M / 128, 4);
    gemm1_kernel<<<g1, 256, 0, stream>>>(Xbf, Whg_bf, CV);

    scan1_kernel<<<(8 * NC * 512) / 256, 256, 0, stream>>>(CV, agg);
    scan2_kernel<<<16, 256, 0, stream>>>(agg, h0);
    scan3_kernel<<<(8 * NC * 512) / 256, 256, 0, stream>>>(CV, h0, Hbf,
                                                           out + (size_t)M * 512);

    dim3 g2(M / 128, 4);
    gemm2_kernel<<<g2, 256, 0, stream>>>(Hbf, Wout_bf, out);
}